// Round 1
// 369.008 us; speedup vs baseline: 1.0118x; 1.0118x over previous
//
#include <hip/hip_runtime.h>

// NeuMF fused inference via f16 MFMA (16x16x32), one wave = 16 samples/tile.
//
// R1 change (latency pipeline): per-tile dependent index loads replaced by ONE
// fully-coalesced user/item load per wave (64 samples = 4 tiles), redistributed
// per tile via __shfl; gather set for tile i+1 is issued BEFORE computing tile
// i (2 named register sets, fully unrolled TPW=4) so HBM gathers stay in
// flight across the compute phase. Everything else identical to baseline.
//
// Structure:
//  - pre-kernel: repack W1 [64,64] and W2 [64,32] (fp32) into f16 MFMA
//    B-fragments in d_ws (frag elem j of lane l = W[kstep*32 + (l>>4)*8 + j][t*16 + (l&15)]).
//  - main kernel: per wave-tile of 16 samples:
//      layer-1 A-frags come DIRECTLY from the gathered mlp rows (k=0..31 = user
//      row, k=32..63 = item row; lane reads row[quad*8..+7]) -> 8 MFMAs.
//      h (bias+relu, f16) round-trips through wave-private LDS into A-layout
//      -> 4 MFMAs for layer 2. Epilogue: relu+b2, dot Wo via LDS partials,
//      lanes 0-15 reduce + GMF (quad-chunked, shfl-xor reduced) -> out.
//  A/B k-pairing is consistent-bijection safe; C/D layout = measured
//  (col=lane&15, row=quad*4+reg), dtype-independent on gfx950.

typedef _Float16 half8 __attribute__((ext_vector_type(8)));
typedef float floatx4 __attribute__((ext_vector_type(4)));

#define WPB 4   // waves per block
#define TPW 4   // tiles per wave (one coalesced 64-sample index load covers all)

__global__ __launch_bounds__(64) void build_frags(const float* __restrict__ W1,
                                                  const float* __restrict__ W2,
                                                  _Float16* __restrict__ wf) {
    const int l = threadIdx.x;
    const int c = l & 15, q = l >> 4;
    // W1 fragments: [s=0..1][t=0..3], 8 frags of 64 lanes x 8 halves
    #pragma unroll
    for (int s = 0; s < 2; ++s)
        #pragma unroll
        for (int t = 0; t < 4; ++t) {
            _Float16* dst = wf + (size_t)((s * 4 + t) * 64 + l) * 8;
            #pragma unroll
            for (int j = 0; j < 8; ++j) {
                const int k = s * 32 + q * 8 + j;
                const int nn = t * 16 + c;
                dst[j] = (_Float16)W1[k * 64 + nn];
            }
        }
    // W2 fragments: [s=0..1][t=0..1], 4 frags, at offset 8*64*8
    _Float16* w2b = wf + 8 * 64 * 8;
    #pragma unroll
    for (int s = 0; s < 2; ++s)
        #pragma unroll
        for (int t = 0; t < 2; ++t) {
            _Float16* dst = w2b + (size_t)((s * 2 + t) * 64 + l) * 8;
            #pragma unroll
            for (int j = 0; j < 8; ++j) {
                const int k = s * 32 + q * 8 + j;
                const int nn = t * 16 + c;
                dst[j] = (_Float16)W2[k * 32 + nn];
            }
        }
}

__global__ __launch_bounds__(256) void neumf_mfma(
    const int* __restrict__ user, const int* __restrict__ item,
    const float* __restrict__ mfu, const float* __restrict__ mfi,
    const float* __restrict__ mlu, const float* __restrict__ mli,
    const _Float16* __restrict__ wf,
    const float* __restrict__ b1, const float* __restrict__ b2,
    const float* __restrict__ Wo, const float* __restrict__ bo,
    float* __restrict__ out, int n)
{
    __shared__ __align__(16) _Float16 x2s[WPB][16 * 72]; // h stage, stride 72 halves (144 B)
    __shared__ __align__(16) float    pss[WPB][16 * 20]; // epilogue partials, stride 20 floats (80 B)

    const int lane = threadIdx.x & 63;
    const int w    = threadIdx.x >> 6;
    const int wave_id = blockIdx.x * WPB + w;
    const int c = lane & 15, q = lane >> 4;

    const int tb = wave_id * (TPW * 16);   // first sample of this wave
    if (tb >= n) return;                   // no barriers in this kernel -> safe

    // ---- resident weight B-fragments (48 VGPRs) ----
    half8 w1f[2][4], w2f[2][2];
    #pragma unroll
    for (int s = 0; s < 2; ++s)
        #pragma unroll
        for (int t = 0; t < 4; ++t)
            w1f[s][t] = *(const half8*)(wf + (size_t)((s * 4 + t) * 64 + lane) * 8);
    const _Float16* w2b = wf + 8 * 64 * 8;
    #pragma unroll
    for (int s = 0; s < 2; ++s)
        #pragma unroll
        for (int t = 0; t < 2; ++t)
            w2f[s][t] = *(const half8*)(w2b + (size_t)((s * 2 + t) * 64 + lane) * 8);

    // per-lane epilogue constants
    const float b1v0 = b1[c], b1v1 = b1[16 + c], b1v2 = b1[32 + c], b1v3 = b1[48 + c];
    const float b2v0 = b2[c], b2v1 = b2[16 + c];
    const float wo2v0 = Wo[16 + c], wo2v1 = Wo[32 + c];
    const float4 wo4 = *(const float4*)(Wo + q * 4);   // GMF chunk of Wo[0:16]
    const float bov = bo[0];

    _Float16* x2 = x2s[w];
    float*    pb = pss[w];

    // ---- ONE coalesced index load for the wave's 64 samples (all 4 tiles) ----
    int gidx = tb + lane; if (gidx >= n) gidx = n - 1;
    const int uAll  = user[gidx];
    const int itAll = item[gidx];

    // Issue tile i's 6 gathers into a named register set. Sample index for
    // lane (c,q) of tile i lives in lane i*16+c of uAll/itAll (one bpermute).
    // OOB tiles issue clamped-but-valid addresses (wasted BW only on the last
    // partial wave); compute/store are guarded instead.
#define ISSUE(i, UA, UB, IA, IB, GU, GI) do {                                  \
        const int u_ = __shfl(uAll,  (i) * 16 + c);                            \
        const int v_ = __shfl(itAll, (i) * 16 + c);                            \
        const float4* pu_ = (const float4*)(mlu + (size_t)u_ * 32 + q * 8);    \
        UA = pu_[0]; UB = pu_[1];                                              \
        const float4* pi_ = (const float4*)(mli + (size_t)v_ * 32 + q * 8);    \
        IA = pi_[0]; IB = pi_[1];                                              \
        GU = *(const float4*)(mfu + (size_t)u_ * 16 + q * 4);                  \
        GI = *(const float4*)(mfi + (size_t)v_ * 16 + q * 4);                  \
    } while (0)

    auto compute = [&](int base, float4 ua, float4 ub, float4 iax, float4 ibx,
                       float4 gu, float4 gi) {
        if (base >= n) return;

        // ---- layer-1 A-fragments straight from the gathered rows ----
        half8 au, ai;
        au[0] = (_Float16)ua.x;  au[1] = (_Float16)ua.y;  au[2] = (_Float16)ua.z;  au[3] = (_Float16)ua.w;
        au[4] = (_Float16)ub.x;  au[5] = (_Float16)ub.y;  au[6] = (_Float16)ub.z;  au[7] = (_Float16)ub.w;
        ai[0] = (_Float16)iax.x; ai[1] = (_Float16)iax.y; ai[2] = (_Float16)iax.z; ai[3] = (_Float16)iax.w;
        ai[4] = (_Float16)ibx.x; ai[5] = (_Float16)ibx.y; ai[6] = (_Float16)ibx.z; ai[7] = (_Float16)ibx.w;

        floatx4 a0 = {0.f,0.f,0.f,0.f}, a1 = {0.f,0.f,0.f,0.f};
        floatx4 a2 = {0.f,0.f,0.f,0.f}, a3 = {0.f,0.f,0.f,0.f};
        a0 = __builtin_amdgcn_mfma_f32_16x16x32_f16(au, w1f[0][0], a0, 0, 0, 0);
        a1 = __builtin_amdgcn_mfma_f32_16x16x32_f16(au, w1f[0][1], a1, 0, 0, 0);
        a2 = __builtin_amdgcn_mfma_f32_16x16x32_f16(au, w1f[0][2], a2, 0, 0, 0);
        a3 = __builtin_amdgcn_mfma_f32_16x16x32_f16(au, w1f[0][3], a3, 0, 0, 0);
        a0 = __builtin_amdgcn_mfma_f32_16x16x32_f16(ai, w1f[1][0], a0, 0, 0, 0);
        a1 = __builtin_amdgcn_mfma_f32_16x16x32_f16(ai, w1f[1][1], a1, 0, 0, 0);
        a2 = __builtin_amdgcn_mfma_f32_16x16x32_f16(ai, w1f[1][2], a2, 0, 0, 0);
        a3 = __builtin_amdgcn_mfma_f32_16x16x32_f16(ai, w1f[1][3], a3, 0, 0, 0);

        // ---- GMF partial (quad-chunked) + cross-quad reduce ----
        float p = gu.x * gi.x * wo4.x + gu.y * gi.y * wo4.y
                + gu.z * gi.z * wo4.z + gu.w * gi.w * wo4.w;
        p += __shfl_xor(p, 16);
        p += __shfl_xor(p, 32);   // all lanes now hold pmf for sample m=c

        // ---- stage h = relu(acc + b1) to LDS as f16 in [m][k] layout ----
        #pragma unroll
        for (int r = 0; r < 4; ++r) {
            const int m = q * 4 + r;     // C/D row = quad*4 + reg (measured)
            x2[m * 72 +  0 + c] = (_Float16)fmaxf(a0[r] + b1v0, 0.f);
            x2[m * 72 + 16 + c] = (_Float16)fmaxf(a1[r] + b1v1, 0.f);
            x2[m * 72 + 32 + c] = (_Float16)fmaxf(a2[r] + b1v2, 0.f);
            x2[m * 72 + 48 + c] = (_Float16)fmaxf(a3[r] + b1v3, 0.f);
        }
        // wave-private LDS; in-order DS pipe + compiler lgkmcnt waits => no barrier

        // ---- layer 2: A-frags from LDS (m = lane&15, k = s*32 + quad*8 + j) ----
        const half8 h0 = *(const half8*)(x2 + c * 72 +  0 + q * 8);
        const half8 h1 = *(const half8*)(x2 + c * 72 + 32 + q * 8);
        floatx4 d0 = {0.f,0.f,0.f,0.f}, d1 = {0.f,0.f,0.f,0.f};
        d0 = __builtin_amdgcn_mfma_f32_16x16x32_f16(h0, w2f[0][0], d0, 0, 0, 0);
        d0 = __builtin_amdgcn_mfma_f32_16x16x32_f16(h1, w2f[1][0], d0, 0, 0, 0);
        d1 = __builtin_amdgcn_mfma_f32_16x16x32_f16(h0, w2f[0][1], d1, 0, 0, 0);
        d1 = __builtin_amdgcn_mfma_f32_16x16x32_f16(h1, w2f[1][1], d1, 0, 0, 0);

        // ---- epilogue: relu(h2 + b2) . Wo[16:48] partials into LDS ----
        #pragma unroll
        for (int r = 0; r < 4; ++r) {
            const float v = fmaxf(d0[r] + b2v0, 0.f) * wo2v0
                          + fmaxf(d1[r] + b2v1, 0.f) * wo2v1;
            pb[(q * 4 + r) * 20 + c] = v;
        }

        if (lane < 16) {
            const float4* row = (const float4*)(pb + lane * 20);
            const float4 r0 = row[0], r1 = row[1], r2 = row[2], r3 = row[3];
            const float s16 = (((r0.x + r0.y) + (r0.z + r0.w)) + ((r1.x + r1.y) + (r1.z + r1.w)))
                            + (((r2.x + r2.y) + (r2.z + r2.w)) + ((r3.x + r3.y) + (r3.z + r3.w)));
            if (base + lane < n)
                out[base + lane] = s16 + p + bov;
        }
    };

    // ---- 2-deep gather pipeline over the 4 tiles (two named register sets) ----
    float4 a_ua, a_ub, a_ia, a_ib, a_gu, a_gi;
    float4 b_ua, b_ub, b_ia, b_ib, b_gu, b_gi;

    ISSUE(0, a_ua, a_ub, a_ia, a_ib, a_gu, a_gi);
    ISSUE(1, b_ua, b_ub, b_ia, b_ib, b_gu, b_gi);

    compute(tb + 0 * 16, a_ua, a_ub, a_ia, a_ib, a_gu, a_gi);
    ISSUE(2, a_ua, a_ub, a_ia, a_ib, a_gu, a_gi);

    compute(tb + 1 * 16, b_ua, b_ub, b_ia, b_ib, b_gu, b_gi);
    ISSUE(3, b_ua, b_ub, b_ia, b_ib, b_gu, b_gi);

    compute(tb + 2 * 16, a_ua, a_ub, a_ia, a_ib, a_gu, a_gi);
    compute(tb + 3 * 16, b_ua, b_ub, b_ia, b_ib, b_gu, b_gi);

#undef ISSUE
}

extern "C" void kernel_launch(void* const* d_in, const int* in_sizes, int n_in,
                              void* d_out, int out_size, void* d_ws, size_t ws_size,
                              hipStream_t stream) {
    const int*   user = (const int*)  d_in[0];
    const int*   item = (const int*)  d_in[1];
    const float* mfu  = (const float*)d_in[2];
    const float* mfi  = (const float*)d_in[3];
    const float* mlu  = (const float*)d_in[4];
    const float* mli  = (const float*)d_in[5];
    const float* W1   = (const float*)d_in[6];
    const float* b1   = (const float*)d_in[7];
    const float* W2   = (const float*)d_in[8];
    const float* b2   = (const float*)d_in[9];
    const float* Wo   = (const float*)d_in[10];
    const float* bo   = (const float*)d_in[11];
    float* out = (float*)d_out;
    _Float16* wf = (_Float16*)d_ws;   // 12 frags x 64 lanes x 8 halves = 12 KB

    build_frags<<<1, 64, 0, stream>>>(W1, W2, wf);

    const int n = in_sizes[0];
    const int tiles  = (n + 15) / 16;
    const int waves  = (tiles + TPW - 1) / TPW;
    const int blocks = (waves + WPB - 1) / WPB;
    neumf_mfma<<<blocks, 256, 0, stream>>>(user, item, mfu, mfi, mlu, mli,
                                           wf, b1, b2, Wo, bo, out, n);
}